// Round 4
// baseline (1306.667 us; speedup 1.0000x reference)
//
#include <hip/hip_runtime.h>

// ---- problem constants (setup_inputs is fixed: H=W=768) ----
#define IMH 768
#define IMW 768
#define NPIX (IMH*IMW)

#define HDC __host__ __device__ constexpr

// factorial table 0..19 (19! exact in double: odd part < 2^53)
struct FTab {
  double f[20];
  constexpr FTab() : f{} { f[0] = 1.0; for (int i = 1; i < 20; ++i) f[i] = f[i-1] * (double)i; }
};
constexpr FTab FTBL;

HDC double csqrt(double x){
  if (x <= 0.0) return 0.0;
  double g = 1.0, y = x;
  while (y >= 4.0){ y *= 0.25; g *= 2.0; }
  while (y < 0.25){ y *= 4.0; g *= 0.5; }
  double r = 1.0;
  for (int i = 0; i < 12; ++i) r = 0.5*(r + y/r);
  return g * r;
}

// Racah formula, verbatim transcription of the reference _su2_cg
HDC double su2cg(int j1,int j2,int j3,int m1,int m2,int m3){
  if (m1 + m2 != m3) return 0.0;
  const double* F = FTBL.f;
  double pref0 = (2.0*j3+1.0)*F[j1+j2-j3]*F[j1-j2+j3]*F[-j1+j2+j3]/F[j1+j2+j3+1];
  double pref  = csqrt(pref0*F[j3+m3]*F[j3-m3]*F[j1-m1]*F[j1+m1]*F[j2-m2]*F[j2+m2]);
  int kmin = 0;
  if (-(j3-j2+m1) > kmin) kmin = -(j3-j2+m1);
  if (-(j3-j1-m2) > kmin) kmin = -(j3-j1-m2);
  int kmax = j1+j2-j3;
  if (j1-m1 < kmax) kmax = j1-m1;
  if (j2+m2 < kmax) kmax = j2+m2;
  double s = 0.0;
  for (int k = kmin; k <= kmax; ++k){
    double t = 1.0/(F[k]*F[j1+j2-j3-k]*F[j1-m1-k]*F[j2+m2-k]*F[j3-j2+m1+k]*F[j3-j1-m2+k]);
    s += (k & 1) ? -t : t;
  }
  return pref * s;
}

// memoized complex CG tensors (keeps each later constexpr var under step budget)
struct CGTab { double c[13][13][13]; };   // [j1+m1][j2+m2][j3+m3]
HDC CGTab make_cg(int j1,int j2,int j3){
  CGTab t{};
  for (int m1 = -j1; m1 <= j1; ++m1)
    for (int m2 = -j2; m2 <= j2; ++m2){
      int m3 = m1 + m2;
      if (m3 < -j3 || m3 > j3) continue;
      t.c[j1+m1][j2+m2][j3+m3] = su2cg(j1, j2, j3, m1, m2, m3);
    }
  return t;
}
constexpr CGTab CG444 = make_cg(4,4,4);
constexpr CGTab CG446 = make_cg(4,4,6);
constexpr CGTab CG464 = make_cg(4,6,4);
constexpr CGTab CG466 = make_cg(4,6,6);
constexpr CGTab CG644 = make_cg(6,4,4);
constexpr CGTab CG646 = make_cg(6,4,6);
constexpr CGTab CG664 = make_cg(6,6,4);
constexpr CGTab CG666 = make_cg(6,6,6);

HDC const CGTab& pick_cg(int A,int B,int C){
  return A ? (B ? (C ? CG666 : CG664) : (C ? CG646 : CG644))
           : (B ? (C ? CG466 : CG464) : (C ? CG446 : CG444));
}

struct CQ { double re, im; };

// Faithful transcription of the reference _q(l) ENTRY q[row, col]:
// rows indexed by construction-loop m (row = l+m), columns at l±|m|;
// includes the global (-i)^l phase (real for even l: +1 l=4, -1 l=6).
HDC CQ qent(int l, int row, int col){
  const double s2 = 0.70710678118654752440;
  double ph = ((l % 4) == 2) ? -1.0 : 1.0;
  int mc = row - l, mr = col - l;
  CQ z{0.0, 0.0};
  if (mr == 0){
    if (mc == 0) z = CQ{ph, 0.0};
  } else if (mr > 0){
    if (mc == -mr)      z = CQ{ph * s2, 0.0};
    else if (mc == mr)  z = CQ{((mr & 1) ? -1.0 : 1.0) * ph * s2, 0.0};
  } else {
    int a = -mr;
    if (mc == -a)       z = CQ{0.0, -ph * s2};
    else if (mc == a)   z = CQ{0.0, ((a & 1) ? -1.0 : 1.0) * ph * s2};
  }
  return z;
}

// LITERAL reference entry:
//   Cr[ci,cj,ck] = Re sum_{i',k',n} q1[i',ci] q2[k',cj] conj(q3[ck,n]) C[i',k',n]
// NOTE: n (contracted with C's complex m3 axis) runs over q3's COLUMNS and the
// free output index ck over q3's ROWS — this is what the einsum 'mn' does.
// (Reference tensor = (q3* q3) x canonical-CG: populates BOTH ±m output slots.)
HDC double cr_entry(const CGTab& cg, int l1,int l2,int l3,int ci,int cj,int ck){
  int a1 = ci < l1 ? l1 - ci : ci - l1;
  int a2 = cj < l2 ? l2 - cj : cj - l2;
  int r1[2] = {l1 - a1, l1 + a1}; int n1 = a1 ? 2 : 1;
  int r2[2] = {l2 - a2, l2 + a2}; int n2 = a2 ? 2 : 1;
  double res = 0.0;
  for (int x = 0; x < n1; ++x)
    for (int y = 0; y < n2; ++y){
      int m1 = r1[x] - l1, m2 = r2[y] - l2, m3 = m1 + m2;
      if (m3 < -l3 || m3 > l3) continue;
      double cgv = cg.c[l1+m1][l2+m2][l3+m3];
      if (cgv == 0.0) continue;
      CQ u = qent(l1, r1[x], ci);
      CQ v = qent(l2, r2[y], cj);
      CQ w = qent(l3, ck, l3 + m3);
      if (w.re == 0.0 && w.im == 0.0) continue;
      double pr = u.re*v.re - u.im*v.im;
      double pi = u.re*v.im + u.im*v.re;
      res += (pr*w.re + pi*w.im) * cgv;   // Re(u*v*conj(w)) * C
    }
  return res;
}

// Structural support of the MIXED tensor: |ck-lc| in {|a1-a2|, a1+a2},
// BOTH signs (the q3*q3 mix smears each canonical value into +-m slots).
// slot 0: lc-d, 1: lc+d, 2: lc-s, 3: lc+s; -1 = invalid/duplicate.
HDC int slot_ck(int lc, int i, int la, int j, int lb, int slot){
  int a1 = i < la ? la - i : i - la;
  int a2 = j < lb ? lb - j : j - lb;
  int d = a1 > a2 ? a1 - a2 : a2 - a1;
  int s = a1 + a2;
  int mag = (slot >> 1) ? s : d;
  bool plus = slot & 1;
  if ((slot >> 1) && s == d) return -1;   // sum slots duplicate diff slots
  if (mag > lc) return -1;
  if (mag == 0 && plus) return -1;        // single slot at ck=lc
  return plus ? lc + mag : lc - mag;
}

struct PathTab { float v[13][13][4]; };   // [i][j][slot], 0 if absent

HDC PathTab make_path(int A, int B, int C){
  const CGTab& cg = pick_cg(A, B, C);
  int la = A ? 6 : 4, lb = B ? 6 : 4, lc = C ? 6 : 4;
  double tmp[13][13][4] = {};
  double nrm2 = 0.0;
  for (int i = 0; i <= 2*la; ++i)
    for (int j = 0; j <= 2*lb; ++j)
      for (int slot = 0; slot < 4; ++slot){
        int ck = slot_ck(lc, i, la, j, lb, slot);
        if (ck < 0) continue;
        double val = cr_entry(cg, la, lb, lc, i, j, ck);
        tmp[i][j][slot] = val;
        nrm2 += val * val;
      }
  double inv = 1.0 / csqrt(nrm2);
  PathTab t{};
  for (int i = 0; i < 13; ++i)
    for (int j = 0; j < 13; ++j)
      for (int slot = 0; slot < 4; ++slot)
        t.v[i][j][slot] = (float)(tmp[i][j][slot] * inv);
  return t;
}

constexpr PathTab P000 = make_path(0,0,0);
constexpr PathTab P001 = make_path(0,0,1);
constexpr PathTab P010 = make_path(0,1,0);
constexpr PathTab P011 = make_path(0,1,1);
constexpr PathTab P100 = make_path(1,0,0);
constexpr PathTab P101 = make_path(1,0,1);
constexpr PathTab P110 = make_path(1,1,0);
constexpr PathTab P111 = make_path(1,1,1);

// compile-time sanity: center entries (m=0 x m=0 -> m=0) nonzero; norm == 1
HDC double tab_norm2(const PathTab& t){
  double s = 0.0;
  for (int i = 0; i < 13; ++i)
    for (int j = 0; j < 13; ++j)
      for (int k = 0; k < 4; ++k) s += (double)t.v[i][j][k]*t.v[i][j][k];
  return s;
}
static_assert(P000.v[4][4][0] != 0.0f, "CG(4,4,4;0,0,0) must be nonzero");
static_assert(P111.v[6][6][0] != 0.0f, "CG(6,6,6;0,0,0) must be nonzero");
static_assert(tab_norm2(P000) > 0.999 && tab_norm2(P000) < 1.001, "Frobenius norm 1");
static_assert(tab_norm2(P111) > 0.999 && tab_norm2(P111) < 1.001, "Frobenius norm 1");

HDC float ptv(int a,int b,int c,int i,int j,int slot){
  return a ? (b ? (c ? P111.v[i][j][slot] : P110.v[i][j][slot])
                : (c ? P101.v[i][j][slot] : P100.v[i][j][slot]))
           : (b ? (c ? P011.v[i][j][slot] : P010.v[i][j][slot])
                : (c ? P001.v[i][j][slot] : P000.v[i][j][slot]));
}

// ---------------- fused kernel ----------------

#define TPAD 325                 // LDS row pad

extern "C" __global__ void __launch_bounds__(256)
conv_tp(const float* __restrict__ f4, const float* __restrict__ f6,
        const float* __restrict__ sw, const float* __restrict__ wp,
        float* __restrict__ out){
  __shared__ float feat[22 * TPAD];   // channel-major 18x18 tile, 28.6 KB

  const int tx = threadIdx.x, ty = threadIdx.y;
  const int tid = ty * 16 + tx;
  const int bx = blockIdx.x * 16, by = blockIdx.y * 16;

  // ---- stage 18x18x22 features into LDS (replicate-clamped) ----
  for (int w = tid; w < 324 * 9; w += 256){
    int pix = w / 9, c = w - pix * 9;
    int ly = pix / 18, lx = pix - ly * 18;
    int gy = by + ly - 1; gy = gy < 0 ? 0 : (gy > IMH-1 ? IMH-1 : gy);
    int gx = bx + lx - 1; gx = gx < 0 ? 0 : (gx > IMW-1 ? IMW-1 : gx);
    feat[c * TPAD + pix] = f4[(gy * IMW + gx) * 9 + c];
  }
  for (int w = tid; w < 324 * 13; w += 256){
    int pix = w / 13, c = w - pix * 13;
    int ly = pix / 18, lx = pix - ly * 18;
    int gy = by + ly - 1; gy = gy < 0 ? 0 : (gy > IMH-1 ? IMH-1 : gy);
    int gx = bx + lx - 1; gx = gx < 0 ? 0 : (gx > IMW-1 ? IMW-1 : gx);
    feat[(9 + c) * TPAD + pix] = f6[(gy * IMW + gx) * 13 + c];
  }
  __syncthreads();

  // ---- per-path scales: alpha * w_paths[p] = 0.5 * w ----
  float pw[8];
  #pragma unroll
  for (int p = 0; p < 8; ++p) pw[p] = 0.5f * wp[p];

  // ---- neighbor average (3x3 cross-correlation) ----
  const float s0 = sw[0], s1 = sw[1], s2 = sw[2],
              s3 = sw[3], s4 = sw[4], s5 = sw[5],
              s6 = sw[6], s7 = sw[7], s8 = sw[8];

  const int lp = (ty + 1) * 18 + (tx + 1);
  float x1[22], x2[22];
  #pragma unroll
  for (int c = 0; c < 22; ++c){
    const float* fr = feat + c * TPAD;
    float ctr = fr[lp];
    x1[c] = ctr;
    x2[c] = s0 * fr[lp - 19] + s1 * fr[lp - 18] + s2 * fr[lp - 17]
          + s3 * fr[lp - 1]  + s4 * ctr         + s5 * fr[lp + 1]
          + s6 * fr[lp + 17] + s7 * fr[lp + 18] + s8 * fr[lp + 19];
  }

  // ---- sparse CG tensor product, compile-time constants folded in ----
  float acc[22];
  #pragma unroll
  for (int k = 0; k < 22; ++k) acc[k] = x1[k];   // residual

  #pragma unroll
  for (int a = 0; a < 2; ++a){
    #pragma unroll
    for (int b = 0; b < 2; ++b){
      const int la = a ? 6 : 4, oA = a ? 9 : 0;
      const int lb = b ? 6 : 4, oB = b ? 9 : 0;
      #pragma unroll
      for (int i = 0; i <= 12; ++i){
        if (i > 2*la) continue;
        #pragma unroll
        for (int j = 0; j <= 12; ++j){
          if (j > 2*lb) continue;
          const float prod = x1[oA + i] * x2[oB + j];
          const float pr0 = prod * pw[a*4 + b*2 + 0];
          const float pr1 = prod * pw[a*4 + b*2 + 1];
          #pragma unroll
          for (int c = 0; c < 2; ++c){
            const int lc = c ? 6 : 4;
            #pragma unroll
            for (int slot = 0; slot < 4; ++slot){
              const int ck = slot_ck(lc, i, la, j, lb, slot);
              if (ck >= 0){
                const float V = ptv(a, b, c, i, j, slot);
                if (V != 0.0f)
                  acc[(c ? 9 : 0) + ck] += V * (c ? pr1 : pr0);
              }
            }
          }
        }
      }
    }
  }

  // ---- store: out0 [N,9] then out1 [N,13], flat-concatenated ----
  const int n = (by + ty) * IMW + (bx + tx);
  float* o0 = out + (size_t)n * 9;
  #pragma unroll
  for (int k = 0; k < 9; ++k) o0[k] = acc[k];
  float* o1 = out + (size_t)NPIX * 9 + (size_t)n * 13;
  #pragma unroll
  for (int k = 0; k < 13; ++k) o1[k] = acc[9 + k];
}

extern "C" void kernel_launch(void* const* d_in, const int* in_sizes, int n_in,
                              void* d_out, int out_size, void* d_ws, size_t ws_size,
                              hipStream_t stream) {
  (void)in_sizes; (void)n_in; (void)out_size; (void)d_ws; (void)ws_size;
  const float* f4 = (const float*)d_in[0];
  const float* f6 = (const float*)d_in[1];
  const float* sw = (const float*)d_in[2];
  const float* wp = (const float*)d_in[3];
  conv_tp<<<dim3(48, 48), dim3(16, 16), 0, stream>>>(f4, f6, sw, wp, (float*)d_out);
}

// Round 6
// 1118.038 us; speedup vs baseline: 1.1687x; 1.1687x over previous
//
#include <hip/hip_runtime.h>

// ---- problem constants (setup_inputs is fixed: H=W=768) ----
#define IMH 768
#define IMW 768
#define NPIX (IMH*IMW)

#define HDC __host__ __device__ constexpr

// factorial table 0..19
struct FTab {
  double f[20];
  constexpr FTab() : f{} { f[0] = 1.0; for (int i = 1; i < 20; ++i) f[i] = f[i-1] * (double)i; }
};
constexpr FTab FTBL;

HDC double csqrt(double x){
  if (x <= 0.0) return 0.0;
  double g = 1.0, y = x;
  while (y >= 4.0){ y *= 0.25; g *= 2.0; }
  while (y < 0.25){ y *= 4.0; g *= 0.5; }
  double r = 1.0;
  for (int i = 0; i < 12; ++i) r = 0.5*(r + y/r);
  return g * r;
}

// Racah formula, verbatim transcription of the reference _su2_cg
HDC double su2cg(int j1,int j2,int j3,int m1,int m2,int m3){
  if (m1 + m2 != m3) return 0.0;
  const double* F = FTBL.f;
  double pref0 = (2.0*j3+1.0)*F[j1+j2-j3]*F[j1-j2+j3]*F[-j1+j2+j3]/F[j1+j2+j3+1];
  double pref  = csqrt(pref0*F[j3+m3]*F[j3-m3]*F[j1-m1]*F[j1+m1]*F[j2-m2]*F[j2+m2]);
  int kmin = 0;
  if (-(j3-j2+m1) > kmin) kmin = -(j3-j2+m1);
  if (-(j3-j1-m2) > kmin) kmin = -(j3-j1-m2);
  int kmax = j1+j2-j3;
  if (j1-m1 < kmax) kmax = j1-m1;
  if (j2+m2 < kmax) kmax = j2+m2;
  double s = 0.0;
  for (int k = kmin; k <= kmax; ++k){
    double t = 1.0/(F[k]*F[j1+j2-j3-k]*F[j1-m1-k]*F[j2+m2-k]*F[j3-j2+m1+k]*F[j3-j1-m2+k]);
    s += (k & 1) ? -t : t;
  }
  return pref * s;
}

// memoized complex CG tensors
struct CGTab { double c[13][13][13]; };   // [j1+m1][j2+m2][j3+m3]
HDC CGTab make_cg(int j1,int j2,int j3){
  CGTab t{};
  for (int m1 = -j1; m1 <= j1; ++m1)
    for (int m2 = -j2; m2 <= j2; ++m2){
      int m3 = m1 + m2;
      if (m3 < -j3 || m3 > j3) continue;
      t.c[j1+m1][j2+m2][j3+m3] = su2cg(j1, j2, j3, m1, m2, m3);
    }
  return t;
}
constexpr CGTab CG444 = make_cg(4,4,4);
constexpr CGTab CG446 = make_cg(4,4,6);
constexpr CGTab CG464 = make_cg(4,6,4);
constexpr CGTab CG466 = make_cg(4,6,6);
constexpr CGTab CG644 = make_cg(6,4,4);
constexpr CGTab CG646 = make_cg(6,4,6);
constexpr CGTab CG664 = make_cg(6,6,4);
constexpr CGTab CG666 = make_cg(6,6,6);

HDC const CGTab& pick_cg(int A,int B,int C){
  return A ? (B ? (C ? CG666 : CG664) : (C ? CG646 : CG644))
           : (B ? (C ? CG466 : CG464) : (C ? CG446 : CG444));
}

struct CQ { double re, im; };

// Faithful transcription of the reference _q(l) ENTRY q[row, col]
HDC CQ qent(int l, int row, int col){
  const double s2 = 0.70710678118654752440;
  double ph = ((l % 4) == 2) ? -1.0 : 1.0;
  int mc = row - l, mr = col - l;
  CQ z{0.0, 0.0};
  if (mr == 0){
    if (mc == 0) z = CQ{ph, 0.0};
  } else if (mr > 0){
    if (mc == -mr)      z = CQ{ph * s2, 0.0};
    else if (mc == mr)  z = CQ{((mr & 1) ? -1.0 : 1.0) * ph * s2, 0.0};
  } else {
    int a = -mr;
    if (mc == -a)       z = CQ{0.0, -ph * s2};
    else if (mc == a)   z = CQ{0.0, ((a & 1) ? -1.0 : 1.0) * ph * s2};
  }
  return z;
}

// literal reference entry (q3 contracted over its COLUMNS, free index = rows)
HDC double cr_entry(const CGTab& cg, int l1,int l2,int l3,int ci,int cj,int ck){
  int a1 = ci < l1 ? l1 - ci : ci - l1;
  int a2 = cj < l2 ? l2 - cj : cj - l2;
  int r1[2] = {l1 - a1, l1 + a1}; int n1 = a1 ? 2 : 1;
  int r2[2] = {l2 - a2, l2 + a2}; int n2 = a2 ? 2 : 1;
  double res = 0.0;
  for (int x = 0; x < n1; ++x)
    for (int y = 0; y < n2; ++y){
      int m1 = r1[x] - l1, m2 = r2[y] - l2, m3 = m1 + m2;
      if (m3 < -l3 || m3 > l3) continue;
      double cgv = cg.c[l1+m1][l2+m2][l3+m3];
      if (cgv == 0.0) continue;
      CQ u = qent(l1, r1[x], ci);
      CQ v = qent(l2, r2[y], cj);
      CQ w = qent(l3, ck, l3 + m3);
      if (w.re == 0.0 && w.im == 0.0) continue;
      double pr = u.re*v.re - u.im*v.im;
      double pi = u.re*v.im + u.im*v.re;
      res += (pr*w.re + pi*w.im) * cgv;
    }
  return res;
}

// support slots of the mixed tensor: ck = lc +- d, lc +- s
HDC int slot_ck(int lc, int i, int la, int j, int lb, int slot){
  int a1 = i < la ? la - i : i - la;
  int a2 = j < lb ? lb - j : j - lb;
  int d = a1 > a2 ? a1 - a2 : a2 - a1;
  int s = a1 + a2;
  int mag = (slot >> 1) ? s : d;
  bool plus = slot & 1;
  if ((slot >> 1) && s == d) return -1;
  if (mag > lc) return -1;
  if (mag == 0 && plus) return -1;
  return plus ? lc + mag : lc - mag;
}

struct PathTab { float v[13][13][4]; };

HDC PathTab make_path(int A, int B, int C){
  const CGTab& cg = pick_cg(A, B, C);
  int la = A ? 6 : 4, lb = B ? 6 : 4, lc = C ? 6 : 4;
  double tmp[13][13][4] = {};
  double nrm2 = 0.0;
  for (int i = 0; i <= 2*la; ++i)
    for (int j = 0; j <= 2*lb; ++j)
      for (int slot = 0; slot < 4; ++slot){
        int ck = slot_ck(lc, i, la, j, lb, slot);
        if (ck < 0) continue;
        double val = cr_entry(cg, la, lb, lc, i, j, ck);
        tmp[i][j][slot] = val;
        nrm2 += val * val;
      }
  double inv = 1.0 / csqrt(nrm2);
  PathTab t{};
  for (int i = 0; i < 13; ++i)
    for (int j = 0; j < 13; ++j)
      for (int slot = 0; slot < 4; ++slot)
        t.v[i][j][slot] = (float)(tmp[i][j][slot] * inv);
  return t;
}

constexpr PathTab P000 = make_path(0,0,0);
constexpr PathTab P001 = make_path(0,0,1);
constexpr PathTab P010 = make_path(0,1,0);
constexpr PathTab P011 = make_path(0,1,1);
constexpr PathTab P100 = make_path(1,0,0);
constexpr PathTab P101 = make_path(1,0,1);
constexpr PathTab P110 = make_path(1,1,0);
constexpr PathTab P111 = make_path(1,1,1);

HDC float ptv(int a,int b,int c,int i,int j,int slot){
  return a ? (b ? (c ? P111.v[i][j][slot] : P110.v[i][j][slot])
                : (c ? P101.v[i][j][slot] : P100.v[i][j][slot]))
           : (b ? (c ? P011.v[i][j][slot] : P010.v[i][j][slot])
                : (c ? P001.v[i][j][slot] : P000.v[i][j][slot]));
}

// ---- flat compile-time entry list (zeros filtered) --------------------
// Round-4 lesson: loop nest not unrolled -> .rodata loads + scratch spills.
// Round-5 lesson: a 2288-term fold expression exceeds -fbracket-depth.
// => binary-recursive template expansion: depth log2(N) ~ 12, flat emission.

struct Ent { int dst, ia, ib, pwi; float v; };

HDC int count_entries(){
  int n = 0;
  for (int a = 0; a < 2; ++a)
    for (int b = 0; b < 2; ++b){
      int la = a ? 6 : 4, lb = b ? 6 : 4;
      for (int i = 0; i <= 2*la; ++i)
        for (int j = 0; j <= 2*lb; ++j)
          for (int c = 0; c < 2; ++c){
            int lc = c ? 6 : 4;
            for (int slot = 0; slot < 4; ++slot){
              int ck = slot_ck(lc, i, la, j, lb, slot);
              if (ck < 0) continue;
              if (ptv(a, b, c, i, j, slot) != 0.0f) n++;
            }
          }
    }
  return n;
}
constexpr int NENT = count_entries();
static_assert(NENT > 800 && NENT < 5000, "entry count sanity");

struct ETab { Ent e[NENT]; };
HDC ETab make_etab(){
  ETab t{};
  int n = 0;
  for (int a = 0; a < 2; ++a)
    for (int b = 0; b < 2; ++b){
      int la = a ? 6 : 4, lb = b ? 6 : 4;
      int oA = a ? 9 : 0, oB = b ? 9 : 0;
      for (int i = 0; i <= 2*la; ++i)
        for (int j = 0; j <= 2*lb; ++j)
          for (int c = 0; c < 2; ++c){
            int lc = c ? 6 : 4;
            for (int slot = 0; slot < 4; ++slot){
              int ck = slot_ck(lc, i, la, j, lb, slot);
              if (ck < 0) continue;
              float v = ptv(a, b, c, i, j, slot);
              if (v != 0.0f){
                t.e[n] = Ent{(c ? 9 : 0) + ck, oA + i, oB + j, a*4 + b*2 + c, v};
                n++;
              }
            }
          }
    }
  return t;
}
constexpr ETab ET = make_etab();

// guaranteed-expanded contraction via binary template recursion: every
// index is a compile-time constant -> acc/x1/x2/pws literal-indexed
// (registers), coefficients are immediates; CSE merges shared (i,j) and
// (p,i,j) subproducts.
template <int Lo, int Hi>
__device__ __attribute__((always_inline)) inline void
tp_range(float* __restrict__ acc, const float* __restrict__ x1,
         const float* __restrict__ x2, const float* __restrict__ pws){
  if constexpr (Hi - Lo == 1){
    constexpr Ent e = ET.e[Lo];
    acc[e.dst] += e.v * (pws[e.pwi] * (x1[e.ia] * x2[e.ib]));
  } else {
    constexpr int Mid = Lo + (Hi - Lo) / 2;
    tp_range<Lo, Mid>(acc, x1, x2, pws);
    tp_range<Mid, Hi>(acc, x1, x2, pws);
  }
}

// ---------------- fused kernel ----------------

#define TPAD 325                 // LDS row pad

extern "C" __global__ void __launch_bounds__(256)
conv_tp(const float* __restrict__ f4, const float* __restrict__ f6,
        const float* __restrict__ sw, const float* __restrict__ wp,
        float* __restrict__ out){
  __shared__ float feat[22 * TPAD];   // channel-major 18x18 tile, 28.6 KB

  const int tx = threadIdx.x, ty = threadIdx.y;
  const int tid = ty * 16 + tx;
  const int bx = blockIdx.x * 16, by = blockIdx.y * 16;

  // ---- stage 18x18x22 features into LDS (replicate-clamped) ----
  for (int w = tid; w < 324 * 9; w += 256){
    int pix = w / 9, c = w - pix * 9;
    int ly = pix / 18, lx = pix - ly * 18;
    int gy = by + ly - 1; gy = gy < 0 ? 0 : (gy > IMH-1 ? IMH-1 : gy);
    int gx = bx + lx - 1; gx = gx < 0 ? 0 : (gx > IMW-1 ? IMW-1 : gx);
    feat[c * TPAD + pix] = f4[(gy * IMW + gx) * 9 + c];
  }
  for (int w = tid; w < 324 * 13; w += 256){
    int pix = w / 13, c = w - pix * 13;
    int ly = pix / 18, lx = pix - ly * 18;
    int gy = by + ly - 1; gy = gy < 0 ? 0 : (gy > IMH-1 ? IMH-1 : gy);
    int gx = bx + lx - 1; gx = gx < 0 ? 0 : (gx > IMW-1 ? IMW-1 : gx);
    feat[(9 + c) * TPAD + pix] = f6[(gy * IMW + gx) * 13 + c];
  }
  __syncthreads();

  // ---- per-path scales: alpha * w_paths[p] = 0.5 * w ----
  float pws[8];
  #pragma unroll
  for (int p = 0; p < 8; ++p) pws[p] = 0.5f * wp[p];

  // ---- neighbor average (3x3 cross-correlation) ----
  const float s0 = sw[0], s1 = sw[1], s2 = sw[2],
              s3 = sw[3], s4 = sw[4], s5 = sw[5],
              s6 = sw[6], s7 = sw[7], s8 = sw[8];

  const int lp = (ty + 1) * 18 + (tx + 1);
  float x1[22], x2[22];
  #pragma unroll
  for (int c = 0; c < 22; ++c){
    const float* fr = feat + c * TPAD;
    float ctr = fr[lp];
    x1[c] = ctr;
    x2[c] = s0 * fr[lp - 19] + s1 * fr[lp - 18] + s2 * fr[lp - 17]
          + s3 * fr[lp - 1]  + s4 * ctr         + s5 * fr[lp + 1]
          + s6 * fr[lp + 17] + s7 * fr[lp + 18] + s8 * fr[lp + 19];
  }

  // ---- sparse CG tensor product, guaranteed-unrolled ----
  float acc[22];
  #pragma unroll
  for (int k = 0; k < 22; ++k) acc[k] = x1[k];   // residual

  tp_range<0, NENT>(acc, x1, x2, pws);

  // ---- store: out0 [N,9] then out1 [N,13], flat-concatenated ----
  const int n = (by + ty) * IMW + (bx + tx);
  float* o0 = out + (size_t)n * 9;
  #pragma unroll
  for (int k = 0; k < 9; ++k) o0[k] = acc[k];
  float* o1 = out + (size_t)NPIX * 9 + (size_t)n * 13;
  #pragma unroll
  for (int k = 0; k < 13; ++k) o1[k] = acc[9 + k];
}

extern "C" void kernel_launch(void* const* d_in, const int* in_sizes, int n_in,
                              void* d_out, int out_size, void* d_ws, size_t ws_size,
                              hipStream_t stream) {
  (void)in_sizes; (void)n_in; (void)out_size; (void)d_ws; (void)ws_size;
  const float* f4 = (const float*)d_in[0];
  const float* f6 = (const float*)d_in[1];
  const float* sw = (const float*)d_in[2];
  const float* wp = (const float*)d_in[3];
  conv_tp<<<dim3(48, 48), dim3(16, 16), 0, stream>>>(f4, f6, sw, wp, (float*)d_out);
}

// Round 7
// 561.658 us; speedup vs baseline: 2.3264x; 1.9906x over previous
//
#include <hip/hip_runtime.h>

// ---- problem constants (setup_inputs is fixed: H=W=768) ----
#define IMH 768
#define IMW 768
#define NPIX (IMH*IMW)

#define HDC __host__ __device__ constexpr

// factorial table 0..19
struct FTab {
  double f[20];
  constexpr FTab() : f{} { f[0] = 1.0; for (int i = 1; i < 20; ++i) f[i] = f[i-1] * (double)i; }
};
constexpr FTab FTBL;

HDC double csqrt(double x){
  if (x <= 0.0) return 0.0;
  double g = 1.0, y = x;
  while (y >= 4.0){ y *= 0.25; g *= 2.0; }
  while (y < 0.25){ y *= 4.0; g *= 0.5; }
  double r = 1.0;
  for (int i = 0; i < 12; ++i) r = 0.5*(r + y/r);
  return g * r;
}

// Racah formula, verbatim transcription of the reference _su2_cg
HDC double su2cg(int j1,int j2,int j3,int m1,int m2,int m3){
  if (m1 + m2 != m3) return 0.0;
  const double* F = FTBL.f;
  double pref0 = (2.0*j3+1.0)*F[j1+j2-j3]*F[j1-j2+j3]*F[-j1+j2+j3]/F[j1+j2+j3+1];
  double pref  = csqrt(pref0*F[j3+m3]*F[j3-m3]*F[j1-m1]*F[j1+m1]*F[j2-m2]*F[j2+m2]);
  int kmin = 0;
  if (-(j3-j2+m1) > kmin) kmin = -(j3-j2+m1);
  if (-(j3-j1-m2) > kmin) kmin = -(j3-j1-m2);
  int kmax = j1+j2-j3;
  if (j1-m1 < kmax) kmax = j1-m1;
  if (j2+m2 < kmax) kmax = j2+m2;
  double s = 0.0;
  for (int k = kmin; k <= kmax; ++k){
    double t = 1.0/(F[k]*F[j1+j2-j3-k]*F[j1-m1-k]*F[j2+m2-k]*F[j3-j2+m1+k]*F[j3-j1-m2+k]);
    s += (k & 1) ? -t : t;
  }
  return pref * s;
}

// memoized complex CG tensors
struct CGTab { double c[13][13][13]; };   // [j1+m1][j2+m2][j3+m3]
HDC CGTab make_cg(int j1,int j2,int j3){
  CGTab t{};
  for (int m1 = -j1; m1 <= j1; ++m1)
    for (int m2 = -j2; m2 <= j2; ++m2){
      int m3 = m1 + m2;
      if (m3 < -j3 || m3 > j3) continue;
      t.c[j1+m1][j2+m2][j3+m3] = su2cg(j1, j2, j3, m1, m2, m3);
    }
  return t;
}
constexpr CGTab CG444 = make_cg(4,4,4);
constexpr CGTab CG446 = make_cg(4,4,6);
constexpr CGTab CG464 = make_cg(4,6,4);
constexpr CGTab CG466 = make_cg(4,6,6);
constexpr CGTab CG644 = make_cg(6,4,4);
constexpr CGTab CG646 = make_cg(6,4,6);
constexpr CGTab CG664 = make_cg(6,6,4);
constexpr CGTab CG666 = make_cg(6,6,6);

HDC const CGTab& pick_cg(int A,int B,int C){
  return A ? (B ? (C ? CG666 : CG664) : (C ? CG646 : CG644))
           : (B ? (C ? CG466 : CG464) : (C ? CG446 : CG444));
}

struct CQ { double re, im; };

// Faithful transcription of the reference _q(l) ENTRY q[row, col]
HDC CQ qent(int l, int row, int col){
  const double s2 = 0.70710678118654752440;
  double ph = ((l % 4) == 2) ? -1.0 : 1.0;
  int mc = row - l, mr = col - l;
  CQ z{0.0, 0.0};
  if (mr == 0){
    if (mc == 0) z = CQ{ph, 0.0};
  } else if (mr > 0){
    if (mc == -mr)      z = CQ{ph * s2, 0.0};
    else if (mc == mr)  z = CQ{((mr & 1) ? -1.0 : 1.0) * ph * s2, 0.0};
  } else {
    int a = -mr;
    if (mc == -a)       z = CQ{0.0, -ph * s2};
    else if (mc == a)   z = CQ{0.0, ((a & 1) ? -1.0 : 1.0) * ph * s2};
  }
  return z;
}

// literal reference entry (q3 contracted over its COLUMNS, free index = rows)
HDC double cr_entry(const CGTab& cg, int l1,int l2,int l3,int ci,int cj,int ck){
  int a1 = ci < l1 ? l1 - ci : ci - l1;
  int a2 = cj < l2 ? l2 - cj : cj - l2;
  int r1[2] = {l1 - a1, l1 + a1}; int n1 = a1 ? 2 : 1;
  int r2[2] = {l2 - a2, l2 + a2}; int n2 = a2 ? 2 : 1;
  double res = 0.0;
  for (int x = 0; x < n1; ++x)
    for (int y = 0; y < n2; ++y){
      int m1 = r1[x] - l1, m2 = r2[y] - l2, m3 = m1 + m2;
      if (m3 < -l3 || m3 > l3) continue;
      double cgv = cg.c[l1+m1][l2+m2][l3+m3];
      if (cgv == 0.0) continue;
      CQ u = qent(l1, r1[x], ci);
      CQ v = qent(l2, r2[y], cj);
      CQ w = qent(l3, ck, l3 + m3);
      if (w.re == 0.0 && w.im == 0.0) continue;
      double pr = u.re*v.re - u.im*v.im;
      double pi = u.re*v.im + u.im*v.re;
      res += (pr*w.re + pi*w.im) * cgv;
    }
  return res;
}

// support slots of the mixed tensor: ck = lc +- d, lc +- s
HDC int slot_ck(int lc, int i, int la, int j, int lb, int slot){
  int a1 = i < la ? la - i : i - la;
  int a2 = j < lb ? lb - j : j - lb;
  int d = a1 > a2 ? a1 - a2 : a2 - a1;
  int s = a1 + a2;
  int mag = (slot >> 1) ? s : d;
  bool plus = slot & 1;
  if ((slot >> 1) && s == d) return -1;
  if (mag > lc) return -1;
  if (mag == 0 && plus) return -1;
  return plus ? lc + mag : lc - mag;
}

struct PathTab { float v[13][13][4]; };

HDC PathTab make_path(int A, int B, int C){
  const CGTab& cg = pick_cg(A, B, C);
  int la = A ? 6 : 4, lb = B ? 6 : 4, lc = C ? 6 : 4;
  double tmp[13][13][4] = {};
  double nrm2 = 0.0;
  for (int i = 0; i <= 2*la; ++i)
    for (int j = 0; j <= 2*lb; ++j)
      for (int slot = 0; slot < 4; ++slot){
        int ck = slot_ck(lc, i, la, j, lb, slot);
        if (ck < 0) continue;
        double val = cr_entry(cg, la, lb, lc, i, j, ck);
        tmp[i][j][slot] = val;
        nrm2 += val * val;
      }
  double inv = 1.0 / csqrt(nrm2);
  PathTab t{};
  for (int i = 0; i < 13; ++i)
    for (int j = 0; j < 13; ++j)
      for (int slot = 0; slot < 4; ++slot)
        t.v[i][j][slot] = (float)(tmp[i][j][slot] * inv);
  return t;
}

constexpr PathTab P000 = make_path(0,0,0);
constexpr PathTab P001 = make_path(0,0,1);
constexpr PathTab P010 = make_path(0,1,0);
constexpr PathTab P011 = make_path(0,1,1);
constexpr PathTab P100 = make_path(1,0,0);
constexpr PathTab P101 = make_path(1,0,1);
constexpr PathTab P110 = make_path(1,1,0);
constexpr PathTab P111 = make_path(1,1,1);

HDC float ptv(int a,int b,int c,int i,int j,int slot){
  return a ? (b ? (c ? P111.v[i][j][slot] : P110.v[i][j][slot])
                : (c ? P101.v[i][j][slot] : P100.v[i][j][slot]))
           : (b ? (c ? P011.v[i][j][slot] : P010.v[i][j][slot])
                : (c ? P001.v[i][j][slot] : P000.v[i][j][slot]));
}

// ---- flat compile-time entry list (zeros filtered) --------------------
// R4: loop nest not unrolled -> rodata interpreter. R5: fold expr too deep.
// R6: full expansion OK but pre-RA scheduler hoisted 1400+ subproducts ->
//     VGPR=256 + spills (1.35 GB writes, VALUBusy 8.8%).
// => sched_barrier(0) every 16 entries pins source order; entry order is
//    (i,j)-major so each x1*x2 product's <=8 uses are consecutive.

struct Ent { int dst, ia, ib, pwi; float v; };

HDC int count_entries(){
  int n = 0;
  for (int a = 0; a < 2; ++a)
    for (int b = 0; b < 2; ++b){
      int la = a ? 6 : 4, lb = b ? 6 : 4;
      for (int i = 0; i <= 2*la; ++i)
        for (int j = 0; j <= 2*lb; ++j)
          for (int c = 0; c < 2; ++c){
            int lc = c ? 6 : 4;
            for (int slot = 0; slot < 4; ++slot){
              int ck = slot_ck(lc, i, la, j, lb, slot);
              if (ck < 0) continue;
              if (ptv(a, b, c, i, j, slot) != 0.0f) n++;
            }
          }
    }
  return n;
}
constexpr int NENT = count_entries();
static_assert(NENT > 800 && NENT < 5000, "entry count sanity");

struct ETab { Ent e[NENT]; };
HDC ETab make_etab(){
  ETab t{};
  int n = 0;
  for (int a = 0; a < 2; ++a)
    for (int b = 0; b < 2; ++b){
      int la = a ? 6 : 4, lb = b ? 6 : 4;
      int oA = a ? 9 : 0, oB = b ? 9 : 0;
      for (int i = 0; i <= 2*la; ++i)
        for (int j = 0; j <= 2*lb; ++j)
          for (int c = 0; c < 2; ++c){
            int lc = c ? 6 : 4;
            for (int slot = 0; slot < 4; ++slot){
              int ck = slot_ck(lc, i, la, j, lb, slot);
              if (ck < 0) continue;
              float v = ptv(a, b, c, i, j, slot);
              if (v != 0.0f){
                t.e[n] = Ent{(c ? 9 : 0) + ck, oA + i, oB + j, a*4 + b*2 + c, v};
                n++;
              }
            }
          }
    }
  return t;
}
constexpr ETab ET = make_etab();

// one entry, all indices compile-time
template <int I>
__device__ __attribute__((always_inline)) inline void
tp_one(float* __restrict__ acc, const float* __restrict__ x1,
       const float* __restrict__ x2, const float* __restrict__ pws){
  constexpr Ent e = ET.e[I];
  acc[e.dst] += e.v * (pws[e.pwi] * (x1[e.ia] * x2[e.ib]));
}

template <int Lo, int Hi>
__device__ __attribute__((always_inline)) inline void
tp_leaf(float* __restrict__ acc, const float* __restrict__ x1,
        const float* __restrict__ x2, const float* __restrict__ pws){
  tp_one<Lo>(acc, x1, x2, pws);
  if constexpr (Lo + 1 < Hi)
    tp_leaf<Lo + 1, Hi>(acc, x1, x2, pws);
}

// binary recursion; at <=16-entry leaves, emit entries then pin the schedule
template <int Lo, int Hi>
__device__ __attribute__((always_inline)) inline void
tp_range(float* __restrict__ acc, const float* __restrict__ x1,
         const float* __restrict__ x2, const float* __restrict__ pws){
  if constexpr (Hi - Lo <= 16){
    tp_leaf<Lo, Hi>(acc, x1, x2, pws);
    __builtin_amdgcn_sched_barrier(0);   // cap live-range growth: no cross-window hoisting
  } else {
    constexpr int Mid = Lo + (Hi - Lo) / 2;
    tp_range<Lo, Mid>(acc, x1, x2, pws);
    tp_range<Mid, Hi>(acc, x1, x2, pws);
  }
}

// ---------------- fused kernel ----------------

#define TPAD 325                 // LDS row pad

extern "C" __global__ void __launch_bounds__(256)
conv_tp(const float* __restrict__ f4, const float* __restrict__ f6,
        const float* __restrict__ sw, const float* __restrict__ wp,
        float* __restrict__ out){
  __shared__ float feat[22 * TPAD];   // channel-major 18x18 tile, 28.6 KB

  const int tx = threadIdx.x, ty = threadIdx.y;
  const int tid = ty * 16 + tx;
  const int bx = blockIdx.x * 16, by = blockIdx.y * 16;

  // ---- stage 18x18x22 features into LDS (replicate-clamped) ----
  for (int w = tid; w < 324 * 9; w += 256){
    int pix = w / 9, c = w - pix * 9;
    int ly = pix / 18, lx = pix - ly * 18;
    int gy = by + ly - 1; gy = gy < 0 ? 0 : (gy > IMH-1 ? IMH-1 : gy);
    int gx = bx + lx - 1; gx = gx < 0 ? 0 : (gx > IMW-1 ? IMW-1 : gx);
    feat[c * TPAD + pix] = f4[(gy * IMW + gx) * 9 + c];
  }
  for (int w = tid; w < 324 * 13; w += 256){
    int pix = w / 13, c = w - pix * 13;
    int ly = pix / 18, lx = pix - ly * 18;
    int gy = by + ly - 1; gy = gy < 0 ? 0 : (gy > IMH-1 ? IMH-1 : gy);
    int gx = bx + lx - 1; gx = gx < 0 ? 0 : (gx > IMW-1 ? IMW-1 : gx);
    feat[(9 + c) * TPAD + pix] = f6[(gy * IMW + gx) * 13 + c];
  }
  __syncthreads();

  // ---- per-path scales: alpha * w_paths[p] = 0.5 * w ----
  float pws[8];
  #pragma unroll
  for (int p = 0; p < 8; ++p) pws[p] = 0.5f * wp[p];

  // ---- neighbor average (3x3 cross-correlation) ----
  const float s0 = sw[0], s1 = sw[1], s2 = sw[2],
              s3 = sw[3], s4 = sw[4], s5 = sw[5],
              s6 = sw[6], s7 = sw[7], s8 = sw[8];

  const int lp = (ty + 1) * 18 + (tx + 1);
  float x1[22], x2[22];
  #pragma unroll
  for (int c = 0; c < 22; ++c){
    const float* fr = feat + c * TPAD;
    float ctr = fr[lp];
    x1[c] = ctr;
    x2[c] = s0 * fr[lp - 19] + s1 * fr[lp - 18] + s2 * fr[lp - 17]
          + s3 * fr[lp - 1]  + s4 * ctr         + s5 * fr[lp + 1]
          + s6 * fr[lp + 17] + s7 * fr[lp + 18] + s8 * fr[lp + 19];
  }

  // ---- sparse CG tensor product, guaranteed-unrolled, schedule-pinned ----
  float acc[22];
  #pragma unroll
  for (int k = 0; k < 22; ++k) acc[k] = x1[k];   // residual

  tp_range<0, NENT>(acc, x1, x2, pws);

  // ---- store: out0 [N,9] then out1 [N,13], flat-concatenated ----
  const int n = (by + ty) * IMW + (bx + tx);
  float* o0 = out + (size_t)n * 9;
  #pragma unroll
  for (int k = 0; k < 9; ++k) o0[k] = acc[k];
  float* o1 = out + (size_t)NPIX * 9 + (size_t)n * 13;
  #pragma unroll
  for (int k = 0; k < 13; ++k) o1[k] = acc[9 + k];
}

extern "C" void kernel_launch(void* const* d_in, const int* in_sizes, int n_in,
                              void* d_out, int out_size, void* d_ws, size_t ws_size,
                              hipStream_t stream) {
  (void)in_sizes; (void)n_in; (void)out_size; (void)d_ws; (void)ws_size;
  const float* f4 = (const float*)d_in[0];
  const float* f6 = (const float*)d_in[1];
  const float* sw = (const float*)d_in[2];
  const float* wp = (const float*)d_in[3];
  conv_tp<<<dim3(48, 48), dim3(16, 16), 0, stream>>>(f4, f6, sw, wp, (float*)d_out);
}